// Round 8
// baseline (528.931 us; speedup 1.0000x reference)
//
#include <hip/hip_runtime.h>

static inline int ceil_div(long long a, long long b) { return (int)((a + b - 1) / b); }

typedef __attribute__((ext_vector_type(8))) short bf16x8;
typedef __attribute__((ext_vector_type(4))) float f32x4;

#define TILE 8192          // edges per hist block
#define BKSH 9             // bucket = dst >> 9  (512 dsts per bucket)

__device__ __forceinline__ float lrelu(float t) { return t > 0.f ? t : 0.2f * t; }

__device__ __forceinline__ void atomAddF(float* p, float v) {
  unsafeAtomicAdd(p, v);  // hardware global_atomic_add_f32
}

// float -> bf16 with round-to-nearest-even
__device__ __forceinline__ unsigned int f2bf(float f) {
  unsigned int u = __float_as_uint(f);
  unsigned int r = ((u >> 16) & 1u) + 0x7fffu;
  return (u + r) >> 16;
}

// async 16B-per-lane global->LDS fill: wave-uniform LDS base, per-lane global addr.
__device__ __forceinline__ void gll16(const void* g, void* l) {
  __builtin_amdgcn_global_load_lds((const __attribute__((address_space(1))) void*)g,
                                   (__attribute__((address_space(3))) void*)l, 16, 0, 0);
}

// ---------------- fused one-time prep: weight transposes + zero init ----------------
__global__ void prep(const float* __restrict__ W1, const float* __restrict__ W2,
                     const float* __restrict__ W3, unsigned short* __restrict__ Wt1,
                     unsigned short* __restrict__ Wt2, unsigned short* __restrict__ Wt3,
                     int* __restrict__ cnt, int* __restrict__ tot, float* __restrict__ dout,
                     int CNTSZ, int NBUK) {
  const int j = blockIdx.x * blockDim.x + threadIdx.x;
  if (j < 40960) {
    const float* W; unsigned short* Wt; int local, DOUTv;
    if (j < 16384)      { W = W1; Wt = Wt1; local = j;          DOUTv = 128; }
    else if (j < 32768) { W = W2; Wt = Wt2; local = j - 16384;  DOUTv = 128; }
    else                { W = W3; Wt = Wt3; local = j - 32768;  DOUTv = 64;  }
    const int k = local / DOUTv, n = local % DOUTv;
    Wt[n * 128 + k] = (unsigned short)f2bf(W[local]);
    return;
  }
  int z = j - 40960;
  if (z < CNTSZ) { cnt[z] = 0; return; }
  z -= CNTSZ;
  if (z < NBUK) { tot[z] = 0; return; }
  z -= NBUK;
  if (z < 64) dout[z] = 0.f;
}

// ---------------- MFMA GEMM + attention scores (async LDS staging) ----------------
template<int DOUT, bool XF32>
__launch_bounds__(256)
__global__ void gemm_mfma(const unsigned short* __restrict__ Xb, const float* __restrict__ xf,
                          const unsigned short* __restrict__ Wt,
                          const float* __restrict__ avs, const float* __restrict__ avd,
                          unsigned short* __restrict__ Hb, float* __restrict__ Ss,
                          float* __restrict__ Sd, int N, int RG) {
  constexpr int DIN = 128;
  constexpr int CG = DOUT / 64;     // 2 (DOUT=128) or 1 (DOUT=64)
  constexpr int RPB = 4 / CG;       // row-groups (of 64 rows) per block
  constexpr int SPSR = (CG == 2) ? RPB : 1;
  constexpr int CHR = DOUT / 4;     // 8-B chunks per output row
  constexpr int SWM = CHR / 8;      // epilogue swizzle multiplier (4 or 2)
  constexpr int XR  = RPB * 64;     // X-tile rows

  __shared__ float sps[SPSR][2][64], spd[SPSR][2][64];
  __shared__ uint4 smem4[(DOUT + XR) * 16];   // sWt | sXb, reused as sOut
  unsigned short* sWt = (unsigned short*)smem4;
  unsigned short* sXb = (unsigned short*)smem4 + DOUT * DIN;
  unsigned int*   sO32 = (unsigned int*)smem4;

  const int tid = threadIdx.x;
  const int wv = tid >> 6;                // 0..3
  const int rgl = wv / CG;
  const int cg  = wv % CG;
  const int rg = blockIdx.x * RPB + rgl;
  const bool active = rg < RG;
  const int lane = tid & 63;
  const int l16 = lane & 15, quad = lane >> 4;
  const int row0 = rg * 64, colw0 = cg * 64;
  const int row0blk = blockIdx.x * XR;

  // ---- async Wt staging: wave wv fills rows [wv*DOUT/4, (wv+1)*DOUT/4) ----
#pragma unroll
  for (int i = 0; i < DOUT / 16; i++) {
    const int r4 = wv * (DOUT / 4) + i * 4;         // wave-uniform
    const int r = r4 + (lane >> 4);
    const int ch = (lane & 15) ^ (r & 7);           // inverse swizzle on source
    gll16(Wt + (size_t)r * DIN + ch * 8, sWt + (size_t)r4 * DIN);
  }
  // ---- X staging ----
  if (XF32) {
    // f32 input needs in-register cvt: keep register path with swizzled LDS writes
    for (int c = tid; c < XR * 16; c += 256) {
      const int row = c >> 4, ch = c & 15;
      int m = row0blk + row; if (m > N - 1) m = N - 1;
      const float4 f0 = *(const float4*)(xf + (size_t)m * DIN + ch * 8);
      const float4 f1 = *(const float4*)(xf + (size_t)m * DIN + ch * 8 + 4);
      uint4 v;
      v.x = f2bf(f0.x) | (f2bf(f0.y) << 16);
      v.y = f2bf(f0.z) | (f2bf(f0.w) << 16);
      v.z = f2bf(f1.x) | (f2bf(f1.y) << 16);
      v.w = f2bf(f1.z) | (f2bf(f1.w) << 16);
      *(uint4*)(sXb + ((row * 16 + (ch ^ (row & 7))) << 3)) = v;
    }
  } else {
#pragma unroll
    for (int i = 0; i < XR / 16; i++) {
      const int r4 = wv * (XR / 4) + i * 4;         // wave-uniform
      const int lr = r4 + (lane >> 4);              // local row
      int m = row0blk + lr; if (m > N - 1) m = N - 1;
      const int ch = (lane & 15) ^ (lr & 7);        // inverse swizzle on source
      gll16(Xb + (size_t)m * DIN + ch * 8, sXb + (size_t)r4 * DIN);
    }
  }
  __syncthreads();   // drains vmcnt (global_load_lds) and lgkm (ds_write)

  f32x4 acc[4][4];
  if (active) {
#pragma unroll
    for (int a = 0; a < 4; a++)
#pragma unroll
      for (int c = 0; c < 4; c++) acc[a][c] = (f32x4)0.f;

#pragma unroll
    for (int kk = 0; kk < 4; kk++) {
      const int chn = kk * 4 + quad;            // nominal 16B chunk
      const int chs = chn ^ (l16 & 7);          // swizzled (row&7 == l16&7 for all tiles)
      bf16x8 aw[4], bx[4];
#pragma unroll
      for (int t = 0; t < 4; t++) {
        const int wrow = colw0 + t * 16 + l16;
        aw[t] = *(const bf16x8*)(sWt + ((wrow * 16 + chs) << 3));
      }
#pragma unroll
      for (int t = 0; t < 4; t++) {
        const int xrow = rgl * 64 + t * 16 + l16;
        bx[t] = *(const bf16x8*)(sXb + ((xrow * 16 + chs) << 3));
      }
#pragma unroll
      for (int wt = 0; wt < 4; wt++)
#pragma unroll
        for (int xt = 0; xt < 4; xt++)
          acc[wt][xt] = __builtin_amdgcn_mfma_f32_16x16x32_bf16(aw[wt], bx[xt], acc[wt][xt], 0, 0, 0);
    }

    // ---- attention-score partials (registers + sps/spd only) ----
    float4 af[4], df[4];
#pragma unroll
    for (int wt = 0; wt < 4; wt++) {
      af[wt] = *(const float4*)(avs + colw0 + wt * 16 + quad * 4);
      df[wt] = *(const float4*)(avd + colw0 + wt * 16 + quad * 4);
    }
#pragma unroll
    for (int xt = 0; xt < 4; xt++) {
      const int m = row0 + xt * 16 + l16;
      float ps = 0.f, pd = 0.f;
#pragma unroll
      for (int wt = 0; wt < 4; wt++) {
        const f32x4 c = acc[wt][xt];
        ps += c[0]*af[wt].x + c[1]*af[wt].y + c[2]*af[wt].z + c[3]*af[wt].w;
        pd += c[0]*df[wt].x + c[1]*df[wt].y + c[2]*df[wt].z + c[3]*df[wt].w;
      }
      ps += __shfl_xor(ps, 16); ps += __shfl_xor(ps, 32);
      pd += __shfl_xor(pd, 16); pd += __shfl_xor(pd, 32);
      if (quad == 0) {
        if (CG == 2) {
          sps[rgl][cg][xt * 16 + l16] = ps;
          spd[rgl][cg][xt * 16 + l16] = pd;
        } else if (m < N) {
          Ss[m] = ps; Sd[m] = pd;
        }
      }
    }
  }

  // all waves done reading sWt/sXb -> reuse smem as output tile
  __syncthreads();

  if (active) {
#pragma unroll
    for (int xt = 0; xt < 4; xt++) {
      const int rl = rgl * 64 + xt * 16 + l16;            // local output row
      const int swz = (rl & 7) * SWM;
#pragma unroll
      for (int wt = 0; wt < 4; wt++) {
        const f32x4 c = acc[wt][xt];
        const int ch = (colw0 >> 2) + wt * 4 + quad;      // 8-B chunk in row
        const int sch = ch ^ swz;
        sO32[rl * (2 * CHR) + 2 * sch]     = f2bf(c[0]) | (f2bf(c[1]) << 16);
        sO32[rl * (2 * CHR) + 2 * sch + 1] = f2bf(c[2]) | (f2bf(c[3]) << 16);
      }
    }
  }
  if (CG == 2 && active && cg == 0) {
    const int m = row0 + lane;
    if (m < N) {
      Ss[m] = sps[rgl][0][lane] + sps[rgl][1][lane];
      Sd[m] = spd[rgl][0][lane] + spd[rgl][1][lane];
    }
  }
  __syncthreads();

  // ---- coalesced Hb store: consecutive lanes -> consecutive 8-B chunks ----
  for (int c = tid; c < XR * CHR; c += 256) {
    const int row = c / CHR, ch = c % CHR;
    const int m = row0blk + row;
    if (m < N) {
      const int sch = ch ^ ((row & 7) * SWM);
      uint2 v = make_uint2(sO32[row * (2 * CHR) + 2 * sch],
                           sO32[row * (2 * CHR) + 2 * sch + 1]);
      *(uint2*)(Hb + (size_t)m * DOUT + ch * 4) = v;
    }
  }
}

// ---------------- direct CSR build: 2 edge passes + tiny scans ----------------
// r7 proved random 4-B writes/atomics on L2-resident data are cheap -> drop the
// bucket-sort machinery (pairs buffer, region_build LDS double-sort) entirely.
// Pass 1: per-dst histogram (global atomics over 400 KB) + per-bucket totals.
__launch_bounds__(256)
__global__ void bucket_hist(const int* __restrict__ dstv, int* __restrict__ cnt,
                            int* __restrict__ tot, int E, int NBUK) {
  __shared__ int h[256];
  h[threadIdx.x] = 0;
  __syncthreads();
  const int base = blockIdx.x * TILE;
  const int end = min(E, base + TILE);
  for (int i = base + threadIdx.x; i < end; i += 256) {
    const int d = dstv[i];
    atomicAdd(&h[d >> BKSH], 1);
    atomicAdd(&cnt[d], 1);
  }
  __syncthreads();
  if (threadIdx.x < NBUK) {
    const int v = h[threadIdx.x];
    if (v) atomicAdd(&tot[threadIdx.x], v);
  }
}

// single block: exclusive scan of per-bucket totals -> bucketBase
__launch_bounds__(256)
__global__ void scan_tot(const int* __restrict__ tot, int* __restrict__ bucketBase,
                         int* __restrict__ rowptr_N, int NBUK, int E) {
  __shared__ int sc[256];
  const int t = threadIdx.x;
  int carry = 0;
  for (int c0 = 0; c0 < NBUK; c0 += 256) {
    const int idx = c0 + t;
    const int v = (idx < NBUK) ? tot[idx] : 0;
    sc[t] = v;
    __syncthreads();
    for (int off = 1; off < 256; off <<= 1) {
      int u = (t >= off) ? sc[t - off] : 0;
      __syncthreads();
      sc[t] += u;
      __syncthreads();
    }
    if (idx < NBUK) bucketBase[idx] = carry + sc[t] - v;
    carry += sc[255];
    __syncthreads();
  }
  if (t == 0) { bucketBase[NBUK] = E; *rowptr_N = E; }
}

// block r: 512-wide local exclusive scan of cnt[r*512..] + bucketBase[r] -> rowptr, wcnt
__launch_bounds__(256)
__global__ void rowptr_build(const int* __restrict__ cnt, const int* __restrict__ bucketBase,
                             int* __restrict__ rowptr, int* __restrict__ wcnt, int N) {
  __shared__ int ps[256];
  const int t = threadIdx.x;
  const int r = blockIdx.x;
  const int base = r << BKSH;
  const int c0 = cnt[base + 2 * t], c1 = cnt[base + 2 * t + 1];
  const int pr = c0 + c1;
  ps[t] = pr;
  __syncthreads();
  for (int off = 1; off < 256; off <<= 1) {
    int v = (t >= off) ? ps[t - off] : 0;
    __syncthreads();
    ps[t] += v;
    __syncthreads();
  }
  const int pbase = bucketBase[r] + ps[t] - pr;
  const int d0 = base + 2 * t, d1 = d0 + 1;
  if (d0 < N) { rowptr[d0] = pbase;      wcnt[d0] = pbase; }
  if (d1 < N) { rowptr[d1] = pbase + c0; wcnt[d1] = pbase + c0; }
}

// Pass 2: place each edge at its final CSR slot via atomic ticket.
__launch_bounds__(256)
__global__ void edge_scatter(const int* __restrict__ src, const int* __restrict__ dstv,
                             int* __restrict__ wcnt, int* __restrict__ srcs, int E) {
  const int i = blockIdx.x * blockDim.x + threadIdx.x;
  if (i < E) {
    const int pos = atomicAdd(&wcnt[dstv[i]], 1);
    srcs[pos] = src[i];
  }
}

// ---------------- fused per-dst gather: block-cooperative, latency-optimized ----------------
// MEANRED: layer 3 writes per-block 64-col partial sums (GGx64) reduced later by mean64.
template<int DOUT, bool OBF, bool MEANRED>
__launch_bounds__(256)
__global__ void node_gather(const int* __restrict__ rowptr, const int* __restrict__ srcs,
                            const float* __restrict__ Ss, const float* __restrict__ Sd,
                            const unsigned short* __restrict__ Hb, const float* __restrict__ b,
                            float* __restrict__ out, unsigned short* __restrict__ outb, int N) {
  constexpr int EPL = DOUT / 16;          // bf16 elems per lane (8 or 4)
  constexpr int WIN = 512;                // edges per block-window (block avg ~256)
  __shared__ uint2 s_sw[WIN];             // (src, w) stash
  __shared__ int   rp[17];
  __shared__ float sdv[16];
  __shared__ float s_mean[64];

  const int tid = threadIdx.x;
  const int l16 = tid & 15;
  const int grp = tid >> 4;
  const int node0 = blockIdx.x * 16;
  const int node = node0 + grp;           // may be >= N (guarded)
  const bool nvalid = node < N;

  if (tid < 17) rp[tid] = rowptr[min(node0 + tid, N)];
  if (tid < 16) sdv[tid] = (node0 + tid < N) ? Sd[node0 + tid] : 0.f;
  if (MEANRED && tid < 64) s_mean[tid] = 0.f;
  __syncthreads();

  const int base = rp[0], endE = rp[16];
  const int r0 = rp[grp], r1 = rp[grp + 1];
  const float sd = sdv[grp];

  float acc[EPL];
#pragma unroll
  for (int k = 0; k < EPL; k++) acc[k] = 0.f;
  float lsum = 0.f;
  const int colb = l16 * EPL;

  for (int wb = base; wb < endE; wb += WIN) {
    if (wb != base) __syncthreads();      // protect stash reuse across windows
    // ---- phase 1: block-parallel (s,w) ----
#pragma unroll
    for (int k0 = 0; k0 < WIN; k0 += 256) {
      const int k = k0 + tid;
      const int i = wb + k;
      if (i < endE) {
        const int s = srcs[i];
        int o = 0;
#pragma unroll
        for (int st = 8; st; st >>= 1)
          if (rp[o + st] <= i) o += st;
        const float w = __expf(lrelu(Ss[s] + sdv[o]));
        s_sw[k] = make_uint2((unsigned)s, __float_as_uint(w));
      }
    }
    __syncthreads();

    // ---- phase 2: per-group 8-deep consumption ----
    const int lo = max(r0, wb), hi = min(r1, wb + WIN);
    const int cnt = hi - lo;
    const int L = lo - wb;
    for (int t = l16; t < cnt; t += 16) lsum += __uint_as_float(s_sw[L + t].y);

    int t = 0;
    for (; t + 8 <= cnt; t += 8) {
      uint2 sw[8];
#pragma unroll
      for (int q = 0; q < 8; q++) sw[q] = s_sw[L + t + q];
      if (EPL == 8) {
        uint4 u[8];
#pragma unroll
        for (int q = 0; q < 8; q++) u[q] = *(const uint4*)(Hb + ((size_t)sw[q].x * DOUT) + colb);
#pragma unroll
        for (int q = 0; q < 8; q++) {
          const float w = __uint_as_float(sw[q].y);
          const unsigned int a[4] = {u[q].x, u[q].y, u[q].z, u[q].w};
#pragma unroll
          for (int k = 0; k < 4; k++) {
            acc[2*k]   += __uint_as_float(a[k] << 16) * w;
            acc[2*k+1] += __uint_as_float(a[k] & 0xffff0000u) * w;
          }
        }
      } else {
        uint2 u[8];
#pragma unroll
        for (int q = 0; q < 8; q++) u[q] = *(const uint2*)(Hb + ((size_t)sw[q].x * DOUT) + colb);
#pragma unroll
        for (int q = 0; q < 8; q++) {
          const float w = __uint_as_float(sw[q].y);
          const unsigned int a[2] = {u[q].x, u[q].y};
#pragma unroll
          for (int k = 0; k < 2; k++) {
            acc[2*k]   += __uint_as_float(a[k] << 16) * w;
            acc[2*k+1] += __uint_as_float(a[k] & 0xffff0000u) * w;
          }
        }
      }
    }
    // predicated 4-deep tail: clamp slot (dup row = L1 hit), zero weight for pads
    for (; t < cnt; t += 4) {
      uint2 sw[4]; float wv[4];
#pragma unroll
      for (int q = 0; q < 4; q++) {
        const int tt = min(t + q, cnt - 1);
        sw[q] = s_sw[L + tt];
        wv[q] = (t + q < cnt) ? __uint_as_float(sw[q].y) : 0.f;
      }
      if (EPL == 8) {
        uint4 u[4];
#pragma unroll
        for (int q = 0; q < 4; q++) u[q] = *(const uint4*)(Hb + ((size_t)sw[q].x * DOUT) + colb);
#pragma unroll
        for (int q = 0; q < 4; q++) {
          const unsigned int a[4] = {u[q].x, u[q].y, u[q].z, u[q].w};
#pragma unroll
          for (int k = 0; k < 4; k++) {
            acc[2*k]   += __uint_as_float(a[k] << 16) * wv[q];
            acc[2*k+1] += __uint_as_float(a[k] & 0xffff0000u) * wv[q];
          }
        }
      } else {
        uint2 u[4];
#pragma unroll
        for (int q = 0; q < 4; q++) u[q] = *(const uint2*)(Hb + ((size_t)sw[q].x * DOUT) + colb);
#pragma unroll
        for (int q = 0; q < 4; q++) {
          const unsigned int a[2] = {u[q].x, u[q].y};
#pragma unroll
          for (int k = 0; k < 2; k++) {
            acc[2*k]   += __uint_as_float(a[k] << 16) * wv[q];
            acc[2*k+1] += __uint_as_float(a[k] & 0xffff0000u) * wv[q];
          }
        }
      }
    }
  }

  // reduce edge-weight sum across the 16-lane group
#pragma unroll
  for (int off = 8; off; off >>= 1) lsum += __shfl_xor(lsum, off);

  // self contribution
  float wself = 0.f;
  if (nvalid) {
    wself = __expf(lrelu(Ss[node] + sd));
    const unsigned short* pp = Hb + (size_t)node * DOUT + colb;
#pragma unroll
    for (int k = 0; k < EPL / 2; k++) {
      const unsigned int u = ((const unsigned int*)pp)[k];
      acc[2*k]   += __uint_as_float(u << 16) * wself;
      acc[2*k+1] += __uint_as_float(u & 0xffff0000u) * wself;
    }
  }

  if (nvalid) {
    const float inv = 1.f / (lsum + wself);
    float o[EPL];
#pragma unroll
    for (int k = 0; k < EPL; k++) o[k] = acc[k] * inv + b[colb + k];
    if (MEANRED) {
#pragma unroll
      for (int k = 0; k < EPL; k++) atomicAdd(&s_mean[colb + k], o[k]);
    } else if (OBF) {
      if (EPL == 8) {
        uint4 u;
        u.x = f2bf(o[0]) | (f2bf(o[1]) << 16);
        u.y = f2bf(o[2]) | (f2bf(o[3]) << 16);
        u.z = f2bf(o[4]) | (f2bf(o[5]) << 16);
        u.w = f2bf(o[6]) | (f2bf(o[7]) << 16);
        *(uint4*)(outb + (size_t)node * DOUT + colb) = u;
      } else {
        uint2 u;
        u.x = f2bf(o[0]) | (f2bf(o[1]) << 16);
        u.y = f2bf(o[2]) | (f2bf(o[3]) << 16);
        *(uint2*)(outb + (size_t)node * DOUT + colb) = u;
      }
    } else {
      float* op = out + (size_t)node * DOUT + colb;
#pragma unroll
      for (int k = 0; k < EPL; k += 4)
        *(float4*)(op + k) = make_float4(o[k], o[k+1], o[k+2], o[k+3]);
    }
  }
  if (MEANRED) {
    __syncthreads();
    if (tid < 64) out[(size_t)blockIdx.x * 64 + tid] = s_mean[tid];
  }
}

// column-wise mean over N rows of a [N,64] matrix (atomic into pre-zeroed d_out)
__global__ void mean64(const float* __restrict__ Hf, float* __restrict__ out, int N, float scale) {
  __shared__ float sm[256];
  const int col = threadIdx.x & 63;
  const int seg = threadIdx.x >> 6;
  const int stride = gridDim.x * 4;
  float s = 0.f;
  for (int n = blockIdx.x * 4 + seg; n < N; n += stride) s += Hf[(size_t)n * 64 + col];
  sm[threadIdx.x] = s;
  __syncthreads();
  if (seg == 0) {
    float tot = sm[col] + sm[64 + col] + sm[128 + col] + sm[192 + col];
    atomAddF(&out[col], tot * scale);
  }
}

extern "C" void kernel_launch(void* const* d_in, const int* in_sizes, int n_in,
                              void* d_out, int out_size, void* d_ws, size_t ws_size,
                              hipStream_t stream) {
  const float* x   = (const float*)d_in[0];
  const int*   ei  = (const int*)d_in[1];
  const float* W1  = (const float*)d_in[2];
  const float* as1 = (const float*)d_in[3];
  const float* ad1 = (const float*)d_in[4];
  const float* b1  = (const float*)d_in[5];
  const float* W2  = (const float*)d_in[6];
  const float* as2 = (const float*)d_in[7];
  const float* ad2 = (const float*)d_in[8];
  const float* b2  = (const float*)d_in[9];
  const float* W3  = (const float*)d_in[10];
  const float* as3 = (const float*)d_in[11];
  const float* ad3 = (const float*)d_in[12];
  const float* b3  = (const float*)d_in[13];

  const int N = in_sizes[0] / 128;
  const int E = in_sizes[1] / 2;
  const int* src  = ei;
  const int* dstv = ei + E;
  const int RG = ceil_div(N, 64);
  const int NBA = ceil_div(E, TILE);
  const int NBUK = ceil_div(N, 1 << BKSH);
  const int CNTSZ = NBUK << BKSH;
  const int GG = ceil_div(N, 16);

  float* p = (float*)d_ws;
  float* part = p; p += (size_t)GG * 64;       // per-block layer-3 partial sums
  float* SsSd = p; p += (size_t)2 * N;
  float* Ss = SsSd, *Sd = SsSd + N;
  unsigned short* Xb = (unsigned short*)p; p += (size_t)N * 64;  // h1/h2 bf16 buffer
  unsigned short* Hb = (unsigned short*)p; p += (size_t)N * 64;
  unsigned short* Wt1 = (unsigned short*)p; p += 128 * 128 / 2;
  unsigned short* Wt2 = (unsigned short*)p; p += 128 * 128 / 2;
  unsigned short* Wt3 = (unsigned short*)p; p += 128 * 64 / 2;
  int* ip = (int*)p;
  int* rowptr     = ip; ip += N + 1;
  int* cnt        = ip; ip += CNTSZ;
  int* wcnt       = ip; ip += CNTSZ;
  int* tot        = ip; ip += NBUK;
  int* bucketBase = ip; ip += NBUK + 1;
  int* srcs       = ip; ip += E;

  // ---- prep: weight transposes + zero(cnt, tot, d_out) ----
  prep<<<ceil_div((long long)40960 + CNTSZ + NBUK + 64, 256), 256, 0, stream>>>(
      W1, W2, W3, Wt1, Wt2, Wt3, cnt, tot, (float*)d_out, CNTSZ, NBUK);

  // ---- CSR build: count -> scan -> place ----
  bucket_hist<<<NBA, 256, 0, stream>>>(dstv, cnt, tot, E, NBUK);
  scan_tot<<<1, 256, 0, stream>>>(tot, bucketBase, rowptr + N, NBUK, E);
  rowptr_build<<<NBUK, 256, 0, stream>>>(cnt, bucketBase, rowptr, wcnt, N);
  edge_scatter<<<ceil_div(E, 256), 256, 0, stream>>>(src, dstv, wcnt, srcs, E);

  // ---- layer 1 (reads f32 x directly) ----
  gemm_mfma<128, true><<<ceil_div(RG, 2), 256, 0, stream>>>(nullptr, x, Wt1, as1, ad1, Hb, Ss, Sd, N, RG);
  node_gather<128, true, false><<<GG, 256, 0, stream>>>(rowptr, srcs, Ss, Sd, Hb, b1, nullptr, Xb, N);
  // ---- layer 2 ----
  gemm_mfma<128, false><<<ceil_div(RG, 2), 256, 0, stream>>>(Xb, nullptr, Wt2, as2, ad2, Hb, Ss, Sd, N, RG);
  node_gather<128, true, false><<<GG, 256, 0, stream>>>(rowptr, srcs, Ss, Sd, Hb, b2, nullptr, Xb, N);
  // ---- layer 3 ----
  gemm_mfma<64, false><<<ceil_div(RG, 4), 256, 0, stream>>>(Xb, nullptr, Wt3, as3, ad3, Hb, Ss, Sd, N, RG);
  node_gather<64, false, true><<<GG, 256, 0, stream>>>(rowptr, srcs, Ss, Sd, Hb, b3, part, nullptr, N);

  mean64<<<256, 256, 0, stream>>>(part, (float*)d_out, GG, 1.0f / (float)N);
}

// Round 9
// 404.162 us; speedup vs baseline: 1.3087x; 1.3087x over previous
//
#include <hip/hip_runtime.h>

static inline int ceil_div(long long a, long long b) { return (int)((a + b - 1) / b); }

typedef __attribute__((ext_vector_type(8))) short bf16x8;
typedef __attribute__((ext_vector_type(4))) float f32x4;

#define TILE 8192          // edges per bucket-pass block
#define BKSH 9             // bucket = dst >> 9  (512 dsts per bucket)

__device__ __forceinline__ float lrelu(float t) { return t > 0.f ? t : 0.2f * t; }

__device__ __forceinline__ void atomAddF(float* p, float v) {
  unsafeAtomicAdd(p, v);  // hardware global_atomic_add_f32
}

// float -> bf16 with round-to-nearest-even
__device__ __forceinline__ unsigned int f2bf(float f) {
  unsigned int u = __float_as_uint(f);
  unsigned int r = ((u >> 16) & 1u) + 0x7fffu;
  return (u + r) >> 16;
}

// async 16B-per-lane global->LDS fill: wave-uniform LDS base, per-lane global addr.
__device__ __forceinline__ void gll16(const void* g, void* l) {
  __builtin_amdgcn_global_load_lds((const __attribute__((address_space(1))) void*)g,
                                   (__attribute__((address_space(3))) void*)l, 16, 0, 0);
}

// ---------------- fused one-time prep: weight transposes + zero init ----------------
__global__ void prep(const float* __restrict__ W1, const float* __restrict__ W2,
                     const float* __restrict__ W3, unsigned short* __restrict__ Wt1,
                     unsigned short* __restrict__ Wt2, unsigned short* __restrict__ Wt3,
                     int* __restrict__ tot, float* __restrict__ dout, int NBUK) {
  const int j = blockIdx.x * blockDim.x + threadIdx.x;
  if (j < 40960) {
    const float* W; unsigned short* Wt; int local, DOUTv;
    if (j < 16384)      { W = W1; Wt = Wt1; local = j;          DOUTv = 128; }
    else if (j < 32768) { W = W2; Wt = Wt2; local = j - 16384;  DOUTv = 128; }
    else                { W = W3; Wt = Wt3; local = j - 32768;  DOUTv = 64;  }
    const int k = local / DOUTv, n = local % DOUTv;
    Wt[n * 128 + k] = (unsigned short)f2bf(W[local]);
    return;
  }
  const int z = j - 40960;
  if (z < NBUK) tot[z] = 0;
  else if (z < NBUK + 64) dout[z - NBUK] = 0.f;
}

// ---------------- MFMA GEMM + attention scores (async LDS staging) ----------------
template<int DOUT, bool XF32>
__launch_bounds__(256)
__global__ void gemm_mfma(const unsigned short* __restrict__ Xb, const float* __restrict__ xf,
                          const unsigned short* __restrict__ Wt,
                          const float* __restrict__ avs, const float* __restrict__ avd,
                          unsigned short* __restrict__ Hb, float* __restrict__ Ss,
                          float* __restrict__ Sd, int N, int RG) {
  constexpr int DIN = 128;
  constexpr int CG = DOUT / 64;     // 2 (DOUT=128) or 1 (DOUT=64)
  constexpr int RPB = 4 / CG;       // row-groups (of 64 rows) per block
  constexpr int SPSR = (CG == 2) ? RPB : 1;
  constexpr int CHR = DOUT / 4;     // 8-B chunks per output row
  constexpr int SWM = CHR / 8;      // epilogue swizzle multiplier (4 or 2)
  constexpr int XR  = RPB * 64;     // X-tile rows

  __shared__ float sps[SPSR][2][64], spd[SPSR][2][64];
  __shared__ uint4 smem4[(DOUT + XR) * 16];   // sWt | sXb, reused as sOut
  unsigned short* sWt = (unsigned short*)smem4;
  unsigned short* sXb = (unsigned short*)smem4 + DOUT * DIN;
  unsigned int*   sO32 = (unsigned int*)smem4;

  const int tid = threadIdx.x;
  const int wv = tid >> 6;                // 0..3
  const int rgl = wv / CG;
  const int cg  = wv % CG;
  const int rg = blockIdx.x * RPB + rgl;
  const bool active = rg < RG;
  const int lane = tid & 63;
  const int l16 = lane & 15, quad = lane >> 4;
  const int row0 = rg * 64, colw0 = cg * 64;
  const int row0blk = blockIdx.x * XR;

  // ---- async Wt staging: wave wv fills rows [wv*DOUT/4, (wv+1)*DOUT/4) ----
#pragma unroll
  for (int i = 0; i < DOUT / 16; i++) {
    const int r4 = wv * (DOUT / 4) + i * 4;         // wave-uniform
    const int r = r4 + (lane >> 4);
    const int ch = (lane & 15) ^ (r & 7);           // inverse swizzle on source
    gll16(Wt + (size_t)r * DIN + ch * 8, sWt + (size_t)r4 * DIN);
  }
  // ---- X staging ----
  if (XF32) {
    // f32 input needs in-register cvt: keep register path with swizzled LDS writes
    for (int c = tid; c < XR * 16; c += 256) {
      const int row = c >> 4, ch = c & 15;
      int m = row0blk + row; if (m > N - 1) m = N - 1;
      const float4 f0 = *(const float4*)(xf + (size_t)m * DIN + ch * 8);
      const float4 f1 = *(const float4*)(xf + (size_t)m * DIN + ch * 8 + 4);
      uint4 v;
      v.x = f2bf(f0.x) | (f2bf(f0.y) << 16);
      v.y = f2bf(f0.z) | (f2bf(f0.w) << 16);
      v.z = f2bf(f1.x) | (f2bf(f1.y) << 16);
      v.w = f2bf(f1.z) | (f2bf(f1.w) << 16);
      *(uint4*)(sXb + ((row * 16 + (ch ^ (row & 7))) << 3)) = v;
    }
  } else {
#pragma unroll
    for (int i = 0; i < XR / 16; i++) {
      const int r4 = wv * (XR / 4) + i * 4;         // wave-uniform
      const int lr = r4 + (lane >> 4);              // local row
      int m = row0blk + lr; if (m > N - 1) m = N - 1;
      const int ch = (lane & 15) ^ (lr & 7);        // inverse swizzle on source
      gll16(Xb + (size_t)m * DIN + ch * 8, sXb + (size_t)r4 * DIN);
    }
  }
  __syncthreads();   // drains vmcnt (global_load_lds) and lgkm (ds_write)

  f32x4 acc[4][4];
  if (active) {
#pragma unroll
    for (int a = 0; a < 4; a++)
#pragma unroll
      for (int c = 0; c < 4; c++) acc[a][c] = (f32x4)0.f;

#pragma unroll
    for (int kk = 0; kk < 4; kk++) {
      const int chn = kk * 4 + quad;            // nominal 16B chunk
      const int chs = chn ^ (l16 & 7);          // swizzled (row&7 == l16&7 for all tiles)
      bf16x8 aw[4], bx[4];
#pragma unroll
      for (int t = 0; t < 4; t++) {
        const int wrow = colw0 + t * 16 + l16;
        aw[t] = *(const bf16x8*)(sWt + ((wrow * 16 + chs) << 3));
      }
#pragma unroll
      for (int t = 0; t < 4; t++) {
        const int xrow = rgl * 64 + t * 16 + l16;
        bx[t] = *(const bf16x8*)(sXb + ((xrow * 16 + chs) << 3));
      }
#pragma unroll
      for (int wt = 0; wt < 4; wt++)
#pragma unroll
        for (int xt = 0; xt < 4; xt++)
          acc[wt][xt] = __builtin_amdgcn_mfma_f32_16x16x32_bf16(aw[wt], bx[xt], acc[wt][xt], 0, 0, 0);
    }

    // ---- attention-score partials (registers + sps/spd only) ----
    float4 af[4], df[4];
#pragma unroll
    for (int wt = 0; wt < 4; wt++) {
      af[wt] = *(const float4*)(avs + colw0 + wt * 16 + quad * 4);
      df[wt] = *(const float4*)(avd + colw0 + wt * 16 + quad * 4);
    }
#pragma unroll
    for (int xt = 0; xt < 4; xt++) {
      const int m = row0 + xt * 16 + l16;
      float ps = 0.f, pd = 0.f;
#pragma unroll
      for (int wt = 0; wt < 4; wt++) {
        const f32x4 c = acc[wt][xt];
        ps += c[0]*af[wt].x + c[1]*af[wt].y + c[2]*af[wt].z + c[3]*af[wt].w;
        pd += c[0]*df[wt].x + c[1]*df[wt].y + c[2]*df[wt].z + c[3]*df[wt].w;
      }
      ps += __shfl_xor(ps, 16); ps += __shfl_xor(ps, 32);
      pd += __shfl_xor(pd, 16); pd += __shfl_xor(pd, 32);
      if (quad == 0) {
        if (CG == 2) {
          sps[rgl][cg][xt * 16 + l16] = ps;
          spd[rgl][cg][xt * 16 + l16] = pd;
        } else if (m < N) {
          Ss[m] = ps; Sd[m] = pd;
        }
      }
    }
  }

  // all waves done reading sWt/sXb -> reuse smem as output tile
  __syncthreads();

  if (active) {
#pragma unroll
    for (int xt = 0; xt < 4; xt++) {
      const int rl = rgl * 64 + xt * 16 + l16;            // local output row
      const int swz = (rl & 7) * SWM;
#pragma unroll
      for (int wt = 0; wt < 4; wt++) {
        const f32x4 c = acc[wt][xt];
        const int ch = (colw0 >> 2) + wt * 4 + quad;      // 8-B chunk in row
        const int sch = ch ^ swz;
        sO32[rl * (2 * CHR) + 2 * sch]     = f2bf(c[0]) | (f2bf(c[1]) << 16);
        sO32[rl * (2 * CHR) + 2 * sch + 1] = f2bf(c[2]) | (f2bf(c[3]) << 16);
      }
    }
  }
  if (CG == 2 && active && cg == 0) {
    const int m = row0 + lane;
    if (m < N) {
      Ss[m] = sps[rgl][0][lane] + sps[rgl][1][lane];
      Sd[m] = spd[rgl][0][lane] + spd[rgl][1][lane];
    }
  }
  __syncthreads();

  // ---- coalesced Hb store: consecutive lanes -> consecutive 8-B chunks ----
  for (int c = tid; c < XR * CHR; c += 256) {
    const int row = c / CHR, ch = c % CHR;
    const int m = row0blk + row;
    if (m < N) {
      const int sch = ch ^ ((row & 7) * SWM);
      uint2 v = make_uint2(sO32[row * (2 * CHR) + 2 * sch],
                           sO32[row * (2 * CHR) + 2 * sch + 1]);
      *(uint2*)(Hb + (size_t)m * DOUT + ch * 4) = v;
    }
  }
}

// ---------------- CSR build: bucket sort, zero global atomics on edges ----------------
__launch_bounds__(256)
__global__ void bucket_hist(const int* __restrict__ dstv, int* __restrict__ bh,
                            int* __restrict__ tot, int E, int NBUK) {
  __shared__ int h[256];
  h[threadIdx.x] = 0;
  __syncthreads();
  const int base = blockIdx.x * TILE;
  const int end = min(E, base + TILE);
  for (int i = base + threadIdx.x; i < end; i += 256)
    atomicAdd(&h[dstv[i] >> BKSH], 1);
  __syncthreads();
  if (threadIdx.x < NBUK) {
    const int v = h[threadIdx.x];
    bh[blockIdx.x * NBUK + threadIdx.x] = v;
    if (v) atomicAdd(&tot[threadIdx.x], v);
  }
}

// blocks 0..NBUK-1: column scan of bh; block NBUK: exclusive scan of tot -> bucketBase
__launch_bounds__(256)
__global__ void scan_fused(int* __restrict__ bh, const int* __restrict__ tot,
                           int* __restrict__ bucketBase, int* __restrict__ rowptr_N,
                           int NBA, int NBUK, int E) {
  __shared__ int sc[256];
  const int t = threadIdx.x;
  if ((int)blockIdx.x < NBUK) {
    const int b = blockIdx.x;
    int carry = 0;
    for (int c0 = 0; c0 < NBA; c0 += 256) {
      const int idx = c0 + t;
      const int v = (idx < NBA) ? bh[idx * NBUK + b] : 0;
      sc[t] = v;
      __syncthreads();
      for (int off = 1; off < 256; off <<= 1) {
        int u = (t >= off) ? sc[t - off] : 0;
        __syncthreads();
        sc[t] += u;
        __syncthreads();
      }
      if (idx < NBA) bh[idx * NBUK + b] = carry + sc[t] - v;
      carry += sc[255];
      __syncthreads();
    }
  } else {
    int carry = 0;
    for (int c0 = 0; c0 < NBUK; c0 += 256) {
      const int idx = c0 + t;
      const int v = (idx < NBUK) ? tot[idx] : 0;
      sc[t] = v;
      __syncthreads();
      for (int off = 1; off < 256; off <<= 1) {
        int u = (t >= off) ? sc[t - off] : 0;
        __syncthreads();
        sc[t] += u;
        __syncthreads();
      }
      if (idx < NBUK) bucketBase[idx] = carry + sc[t] - v;
      carry += sc[255];
      __syncthreads();
    }
    if (t == 0) { bucketBase[NBUK] = E; *rowptr_N = E; }
  }
}

__launch_bounds__(256)
__global__ void bucket_scatter(const int* __restrict__ src, const int* __restrict__ dstv,
                               const int* __restrict__ bh, const int* __restrict__ bucketBase,
                               unsigned int* __restrict__ pairs, int E, int NBUK) {
  __shared__ int ofs[256];
  if (threadIdx.x < NBUK)
    ofs[threadIdx.x] = bh[blockIdx.x * NBUK + threadIdx.x] + bucketBase[threadIdx.x];
  __syncthreads();
  const int base = blockIdx.x * TILE;
  const int end = min(E, base + TILE);
  for (int i = base + threadIdx.x; i < end; i += 256) {
    const int d = dstv[i];
    const int pos = atomicAdd(&ofs[d >> BKSH], 1);
    pairs[pos] = ((unsigned int)src[i] << BKSH) | (unsigned int)(d & ((1 << BKSH) - 1));
  }
}

__launch_bounds__(256)
__global__ void region_build(const unsigned int* __restrict__ pairs,
                             const int* __restrict__ bucketBase,
                             int* __restrict__ rowptr, int* __restrict__ srcs, int N) {
  __shared__ int cnt[512], ofs[512], ps[256];
  const int t = threadIdx.x;
  const int r = blockIdx.x;
  const int p0 = bucketBase[r], p1 = bucketBase[r + 1];
  cnt[t] = 0; cnt[t + 256] = 0;
  __syncthreads();
  for (int i = p0 + t; i < p1; i += 256)
    atomicAdd(&cnt[pairs[i] & 511u], 1);
  __syncthreads();
  const int c0 = cnt[2 * t], c1 = cnt[2 * t + 1];
  const int pr = c0 + c1;
  ps[t] = pr;
  __syncthreads();
  for (int off = 1; off < 256; off <<= 1) {
    int v = (t >= off) ? ps[t - off] : 0;
    __syncthreads();
    ps[t] += v;
    __syncthreads();
  }
  const int pbase = ps[t] - pr;
  ofs[2 * t] = pbase; ofs[2 * t + 1] = pbase + c0;
  __syncthreads();
  {
    const int d0 = (r << BKSH) + t;
    if (d0 < N) rowptr[d0] = p0 + ofs[t];
    const int d1 = (r << BKSH) + t + 256;
    if (d1 < N) rowptr[d1] = p0 + ofs[t + 256];
  }
  __syncthreads();
  for (int i = p0 + t; i < p1; i += 256) {
    const unsigned int w = pairs[i];
    const int pos = atomicAdd(&ofs[w & 511u], 1);
    srcs[p0 + pos] = (int)(w >> BKSH);
  }
}

// ---------------- fused per-dst gather: block-cooperative, latency-optimized ----------------
// MEANRED: layer 3 writes per-block 64-col partial sums (GGx64) reduced later by mean64.
template<int DOUT, bool OBF, bool MEANRED>
__launch_bounds__(256)
__global__ void node_gather(const int* __restrict__ rowptr, const int* __restrict__ srcs,
                            const float* __restrict__ Ss, const float* __restrict__ Sd,
                            const unsigned short* __restrict__ Hb, const float* __restrict__ b,
                            float* __restrict__ out, unsigned short* __restrict__ outb, int N) {
  constexpr int EPL = DOUT / 16;          // bf16 elems per lane (8 or 4)
  constexpr int WIN = 512;                // edges per block-window (block avg ~256)
  __shared__ uint2 s_sw[WIN];             // (src, w) stash
  __shared__ int   rp[17];
  __shared__ float sdv[16];
  __shared__ float s_mean[64];

  const int tid = threadIdx.x;
  const int l16 = tid & 15;
  const int grp = tid >> 4;
  const int node0 = blockIdx.x * 16;
  const int node = node0 + grp;           // may be >= N (guarded)
  const bool nvalid = node < N;

  if (tid < 17) rp[tid] = rowptr[min(node0 + tid, N)];
  if (tid < 16) sdv[tid] = (node0 + tid < N) ? Sd[node0 + tid] : 0.f;
  if (MEANRED && tid < 64) s_mean[tid] = 0.f;
  __syncthreads();

  const int base = rp[0], endE = rp[16];
  const int r0 = rp[grp], r1 = rp[grp + 1];
  const float sd = sdv[grp];

  float acc[EPL];
#pragma unroll
  for (int k = 0; k < EPL; k++) acc[k] = 0.f;
  float lsum = 0.f;
  const int colb = l16 * EPL;

  for (int wb = base; wb < endE; wb += WIN) {
    if (wb != base) __syncthreads();      // protect stash reuse across windows
    // ---- phase 1: block-parallel (s,w) ----
#pragma unroll
    for (int k0 = 0; k0 < WIN; k0 += 256) {
      const int k = k0 + tid;
      const int i = wb + k;
      if (i < endE) {
        const int s = srcs[i];
        int o = 0;
#pragma unroll
        for (int st = 8; st; st >>= 1)
          if (rp[o + st] <= i) o += st;
        const float w = __expf(lrelu(Ss[s] + sdv[o]));
        s_sw[k] = make_uint2((unsigned)s, __float_as_uint(w));
      }
    }
    __syncthreads();

    // ---- phase 2: per-group 8-deep consumption ----
    const int lo = max(r0, wb), hi = min(r1, wb + WIN);
    const int cnt = hi - lo;
    const int L = lo - wb;
    for (int t = l16; t < cnt; t += 16) lsum += __uint_as_float(s_sw[L + t].y);

    int t = 0;
    for (; t + 8 <= cnt; t += 8) {
      uint2 sw[8];
#pragma unroll
      for (int q = 0; q < 8; q++) sw[q] = s_sw[L + t + q];
      if (EPL == 8) {
        uint4 u[8];
#pragma unroll
        for (int q = 0; q < 8; q++) u[q] = *(const uint4*)(Hb + ((size_t)sw[q].x * DOUT) + colb);
#pragma unroll
        for (int q = 0; q < 8; q++) {
          const float w = __uint_as_float(sw[q].y);
          const unsigned int a[4] = {u[q].x, u[q].y, u[q].z, u[q].w};
#pragma unroll
          for (int k = 0; k < 4; k++) {
            acc[2*k]   += __uint_as_float(a[k] << 16) * w;
            acc[2*k+1] += __uint_as_float(a[k] & 0xffff0000u) * w;
          }
        }
      } else {
        uint2 u[8];
#pragma unroll
        for (int q = 0; q < 8; q++) u[q] = *(const uint2*)(Hb + ((size_t)sw[q].x * DOUT) + colb);
#pragma unroll
        for (int q = 0; q < 8; q++) {
          const float w = __uint_as_float(sw[q].y);
          const unsigned int a[2] = {u[q].x, u[q].y};
#pragma unroll
          for (int k = 0; k < 2; k++) {
            acc[2*k]   += __uint_as_float(a[k] << 16) * w;
            acc[2*k+1] += __uint_as_float(a[k] & 0xffff0000u) * w;
          }
        }
      }
    }
    // predicated 4-deep tail: clamp slot (dup row = L1 hit), zero weight for pads
    for (; t < cnt; t += 4) {
      uint2 sw[4]; float wv[4];
#pragma unroll
      for (int q = 0; q < 4; q++) {
        const int tt = min(t + q, cnt - 1);
        sw[q] = s_sw[L + tt];
        wv[q] = (t + q < cnt) ? __uint_as_float(sw[q].y) : 0.f;
      }
      if (EPL == 8) {
        uint4 u[4];
#pragma unroll
        for (int q = 0; q < 4; q++) u[q] = *(const uint4*)(Hb + ((size_t)sw[q].x * DOUT) + colb);
#pragma unroll
        for (int q = 0; q < 4; q++) {
          const unsigned int a[4] = {u[q].x, u[q].y, u[q].z, u[q].w};
#pragma unroll
          for (int k = 0; k < 4; k++) {
            acc[2*k]   += __uint_as_float(a[k] << 16) * wv[q];
            acc[2*k+1] += __uint_as_float(a[k] & 0xffff0000u) * wv[q];
          }
        }
      } else {
        uint2 u[4];
#pragma unroll
        for (int q = 0; q < 4; q++) u[q] = *(const uint2*)(Hb + ((size_t)sw[q].x * DOUT) + colb);
#pragma unroll
        for (int q = 0; q < 4; q++) {
          const unsigned int a[2] = {u[q].x, u[q].y};
#pragma unroll
          for (int k = 0; k < 2; k++) {
            acc[2*k]   += __uint_as_float(a[k] << 16) * wv[q];
            acc[2*k+1] += __uint_as_float(a[k] & 0xffff0000u) * wv[q];
          }
        }
      }
    }
  }

  // reduce edge-weight sum across the 16-lane group
#pragma unroll
  for (int off = 8; off; off >>= 1) lsum += __shfl_xor(lsum, off);

  // self contribution
  float wself = 0.f;
  if (nvalid) {
    wself = __expf(lrelu(Ss[node] + sd));
    const unsigned short* pp = Hb + (size_t)node * DOUT + colb;
#pragma unroll
    for (int k = 0; k < EPL / 2; k++) {
      const unsigned int u = ((const unsigned int*)pp)[k];
      acc[2*k]   += __uint_as_float(u << 16) * wself;
      acc[2*k+1] += __uint_as_float(u & 0xffff0000u) * wself;
    }
  }

  if (nvalid) {
    const float inv = 1.f / (lsum + wself);
    float o[EPL];
#pragma unroll
    for (int k = 0; k < EPL; k++) o[k] = acc[k] * inv + b[colb + k];
    if (MEANRED) {
#pragma unroll
      for (int k = 0; k < EPL; k++) atomicAdd(&s_mean[colb + k], o[k]);
    } else if (OBF) {
      if (EPL == 8) {
        uint4 u;
        u.x = f2bf(o[0]) | (f2bf(o[1]) << 16);
        u.y = f2bf(o[2]) | (f2bf(o[3]) << 16);
        u.z = f2bf(o[4]) | (f2bf(o[5]) << 16);
        u.w = f2bf(o[6]) | (f2bf(o[7]) << 16);
        *(uint4*)(outb + (size_t)node * DOUT + colb) = u;
      } else {
        uint2 u;
        u.x = f2bf(o[0]) | (f2bf(o[1]) << 16);
        u.y = f2bf(o[2]) | (f2bf(o[3]) << 16);
        *(uint2*)(outb + (size_t)node * DOUT + colb) = u;
      }
    } else {
      float* op = out + (size_t)node * DOUT + colb;
#pragma unroll
      for (int k = 0; k < EPL; k += 4)
        *(float4*)(op + k) = make_float4(o[k], o[k+1], o[k+2], o[k+3]);
    }
  }
  if (MEANRED) {
    __syncthreads();
    if (tid < 64) out[(size_t)blockIdx.x * 64 + tid] = s_mean[tid];
  }
}

// column-wise mean over N rows of a [N,64] matrix (atomic into pre-zeroed d_out)
__global__ void mean64(const float* __restrict__ Hf, float* __restrict__ out, int N, float scale) {
  __shared__ float sm[256];
  const int col = threadIdx.x & 63;
  const int seg = threadIdx.x >> 6;
  const int stride = gridDim.x * 4;
  float s = 0.f;
  for (int n = blockIdx.x * 4 + seg; n < N; n += stride) s += Hf[(size_t)n * 64 + col];
  sm[threadIdx.x] = s;
  __syncthreads();
  if (seg == 0) {
    float tot = sm[col] + sm[64 + col] + sm[128 + col] + sm[192 + col];
    atomAddF(&out[col], tot * scale);
  }
}

extern "C" void kernel_launch(void* const* d_in, const int* in_sizes, int n_in,
                              void* d_out, int out_size, void* d_ws, size_t ws_size,
                              hipStream_t stream) {
  const float* x   = (const float*)d_in[0];
  const int*   ei  = (const int*)d_in[1];
  const float* W1  = (const float*)d_in[2];
  const float* as1 = (const float*)d_in[3];
  const float* ad1 = (const float*)d_in[4];
  const float* b1  = (const float*)d_in[5];
  const float* W2  = (const float*)d_in[6];
  const float* as2 = (const float*)d_in[7];
  const float* ad2 = (const float*)d_in[8];
  const float* b2  = (const float*)d_in[9];
  const float* W3  = (const float*)d_in[10];
  const float* as3 = (const float*)d_in[11];
  const float* ad3 = (const float*)d_in[12];
  const float* b3  = (const float*)d_in[13];

  const int N = in_sizes[0] / 128;
  const int E = in_sizes[1] / 2;
  const int* src  = ei;
  const int* dstv = ei + E;
  const int RG = ceil_div(N, 64);
  const int NBA = ceil_div(E, TILE);
  const int NBUK = ceil_div(N, 1 << BKSH);
  const int GG = ceil_div(N, 16);

  float* p = (float*)d_ws;
  float* part = p; p += (size_t)GG * 64;       // per-block layer-3 partial sums
  float* SsSd = p; p += (size_t)2 * N;
  float* Ss = SsSd, *Sd = SsSd + N;
  unsigned short* Xb = (unsigned short*)p; p += (size_t)N * 64;  // h1/h2 bf16 buffer
  unsigned short* Hb = (unsigned short*)p; p += (size_t)N * 64;
  unsigned short* Wt1 = (unsigned short*)p; p += 128 * 128 / 2;
  unsigned short* Wt2 = (unsigned short*)p; p += 128 * 128 / 2;
  unsigned short* Wt3 = (unsigned short*)p; p += 128 * 64 / 2;
  int* ip = (int*)p;
  int* rowptr     = ip; ip += N + 1;
  int* bh         = ip; ip += (size_t)NBA * NBUK;
  int* tot        = ip; ip += NBUK;
  int* bucketBase = ip; ip += NBUK + 1;
  unsigned int* pairs = (unsigned int*)ip; ip += E;
  int* srcs       = ip; ip += E;

  // ---- prep: weight transposes + zero(tot, d_out) ----
  prep<<<ceil_div(40960 + NBUK + 64, 256), 256, 0, stream>>>(
      W1, W2, W3, Wt1, Wt2, Wt3, tot, (float*)d_out, NBUK);

  // ---- CSR build (dst-major) via bucket sort ----
  bucket_hist<<<NBA, 256, 0, stream>>>(dstv, bh, tot, E, NBUK);
  scan_fused<<<NBUK + 1, 256, 0, stream>>>(bh, tot, bucketBase, rowptr + N, NBA, NBUK, E);
  bucket_scatter<<<NBA, 256, 0, stream>>>(src, dstv, bh, bucketBase, pairs, E, NBUK);
  region_build<<<NBUK, 256, 0, stream>>>(pairs, bucketBase, rowptr, srcs, N);

  // ---- layer 1 (reads f32 x directly) ----
  gemm_mfma<128, true><<<ceil_div(RG, 2), 256, 0, stream>>>(nullptr, x, Wt1, as1, ad1, Hb, Ss, Sd, N, RG);
  node_gather<128, true, false><<<GG, 256, 0, stream>>>(rowptr, srcs, Ss, Sd, Hb, b1, nullptr, Xb, N);
  // ---- layer 2 ----
  gemm_mfma<128, false><<<ceil_div(RG, 2), 256, 0, stream>>>(Xb, nullptr, Wt2, as2, ad2, Hb, Ss, Sd, N, RG);
  node_gather<128, true, false><<<GG, 256, 0, stream>>>(rowptr, srcs, Ss, Sd, Hb, b2, nullptr, Xb, N);
  // ---- layer 3 ----
  gemm_mfma<64, false><<<ceil_div(RG, 4), 256, 0, stream>>>(Xb, nullptr, Wt3, as3, ad3, Hb, Ss, Sd, N, RG);
  node_gather<64, false, true><<<GG, 256, 0, stream>>>(rowptr, srcs, Ss, Sd, Hb, b3, part, nullptr, N);

  mean64<<<256, 256, 0, stream>>>(part, (float*)d_out, GG, 1.0f / (float)N);
}